// Round 3
// baseline (792.288 us; speedup 1.0000x reference)
//
#include <hip/hip_runtime.h>
#include <hip/hip_bf16.h>
#include <cmath>

// SparseAttentionBlock: B=2, L=4096, D=512, H=8, dh=64
// Inputs/outputs fp32; internal GEMM pipeline bf16; residual spine fp32.

#define L_SEQ 4096
#define D_MODEL 512
#define N_HEADS 8
#define D_HEAD 64
#define QKV_LD 1536

typedef __attribute__((ext_vector_type(8))) short bf16x8;
typedef __attribute__((ext_vector_type(4))) float f32x4;

__device__ __forceinline__ __hip_bfloat16 f2bf(float v) { return __float2bfloat16(v); }

__device__ __forceinline__ void gl_lds16(const __hip_bfloat16* g, __hip_bfloat16* l) {
  __builtin_amdgcn_global_load_lds((__attribute__((address_space(1))) void*)g,
                                   (__attribute__((address_space(3))) void*)l, 16, 0, 0);
}

// ---------------- fp32 -> bf16 convert (weights) ----------------
__global__ __launch_bounds__(256) void cvt_kernel(const float* __restrict__ src,
                                                  __hip_bfloat16* __restrict__ dst, int n4) {
  const int i = blockIdx.x * 256 + threadIdx.x;
  if (i < n4) {
    const float4 v = ((const float4*)src)[i];
    dst[4 * i + 0] = f2bf(v.x);
    dst[4 * i + 1] = f2bf(v.y);
    dst[4 * i + 2] = f2bf(v.z);
    dst[4 * i + 3] = f2bf(v.w);
  }
}

// ---------------- LayerNorm: fp32 in -> bf16 out ----------------
__global__ __launch_bounds__(256) void ln_kernel(const float* __restrict__ x,
                                                 const float* __restrict__ g,
                                                 const float* __restrict__ b,
                                                 __hip_bfloat16* __restrict__ out) {
  const int row = blockIdx.x;
  const int t = threadIdx.x;
  const float* xr = x + (size_t)row * D_MODEL;
  float v0 = xr[t];
  float v1 = xr[t + 256];
  float s = v0 + v1;
  float qq = v0 * v0 + v1 * v1;
  for (int off = 32; off > 0; off >>= 1) {
    s += __shfl_xor(s, off);
    qq += __shfl_xor(qq, off);
  }
  __shared__ float red[8];
  const int wid = t >> 6;
  if ((t & 63) == 0) { red[wid] = s; red[4 + wid] = qq; }
  __syncthreads();
  s = red[0] + red[1] + red[2] + red[3];
  qq = red[4] + red[5] + red[6] + red[7];
  const float mu = s * (1.0f / 512.0f);
  const float var = fmaxf(qq * (1.0f / 512.0f) - mu * mu, 0.0f);
  const float rstd = rsqrtf(var + 1e-5f);
  __hip_bfloat16* orow = out + (size_t)row * D_MODEL;
  orow[t] = f2bf((v0 - mu) * rstd * g[t] + b[t]);
  orow[t + 256] = f2bf((v1 - mu) * rstd * g[t + 256] + b[t + 256]);
}

// ---------------- V transpose: qkv V-region -> vt[b,h,dh,L] ----------------
__global__ __launch_bounds__(256) void vtrans_kernel(const __hip_bfloat16* __restrict__ qkv,
                                                     __hip_bfloat16* __restrict__ vt) {
  const int gid = blockIdx.x * 256 + threadIdx.x;  // 2*64*4096 threads exactly
  const int l = gid & 4095;
  const int bg = gid >> 12;       // b*64 + g
  const int b = bg >> 6, g = bg & 63;
  const int h = g >> 3, dg = (g & 7) * 8;
  const __hip_bfloat16* src = qkv + (size_t)(b * L_SEQ + l) * QKV_LD + 1024 + h * 64 + dg;
  bf16x8 v = *(const bf16x8*)src;
  const size_t dbase = (size_t)((b * 8 + h) * 64 + dg) * L_SEQ + l;
  for (int j = 0; j < 8; j++)
    vt[dbase + (size_t)j * L_SEQ] = ((const __hip_bfloat16*)&v)[j];  // coalesced over l
}

// ---------------- GEMM: C[M,N] = A[M,K] @ B[N,K]^T, bf16 in, fp32 accum ----------------
// EPI 0: store bf16   1: += aux(fp32), store fp32   2: silu, store bf16   3: += aux(fp32), store fp32
template <int EPI>
__global__ __launch_bounds__(256) void gemm_kernel(const __hip_bfloat16* __restrict__ A,
                                                   const __hip_bfloat16* __restrict__ B,
                                                   int M, int N, int K,
                                                   const float* __restrict__ aux,
                                                   void* __restrict__ C) {
  __shared__ __align__(16) __hip_bfloat16 As[128 * 32];
  __shared__ __align__(16) __hip_bfloat16 Bs[128 * 32];
  const int tid = threadIdx.x;
  const int lane = tid & 63, w = tid >> 6;
  const int m0 = blockIdx.y * 128, n0 = blockIdx.x * 128;
  const int wm = (w >> 1) * 64, wn = (w & 1) * 64;
  const int r = lane & 15, q = lane >> 4;

  f32x4 acc[4][4];
  const f32x4 zz = {0.f, 0.f, 0.f, 0.f};
  for (int i = 0; i < 4; i++)
    for (int j = 0; j < 4; j++) acc[i][j] = zz;

  for (int k0 = 0; k0 < K; k0 += 32) {
    for (int i = 0; i < 2; i++) {
      const int c = i * 256 + tid;
      const int row = c >> 2, kb = (c & 3) * 8;
      gl_lds16(A + (size_t)(m0 + row) * K + (k0 + kb), As + c * 8);
      gl_lds16(B + (size_t)(n0 + row) * K + (k0 + kb), Bs + c * 8);
    }
    __syncthreads();
    bf16x8 af[4], bfr[4];
    for (int mi = 0; mi < 4; mi++)
      af[mi] = *(const bf16x8*)(As + (wm + mi * 16 + r) * 32 + q * 8);
    for (int ni = 0; ni < 4; ni++)
      bfr[ni] = *(const bf16x8*)(Bs + (wn + ni * 16 + r) * 32 + q * 8);
    for (int mi = 0; mi < 4; mi++)
      for (int ni = 0; ni < 4; ni++)
        acc[mi][ni] = __builtin_amdgcn_mfma_f32_16x16x32_bf16(af[mi], bfr[ni], acc[mi][ni], 0, 0, 0);
    __syncthreads();
  }

  for (int mi = 0; mi < 4; mi++)
    for (int ni = 0; ni < 4; ni++)
      for (int j = 0; j < 4; j++) {
        const int gm = m0 + wm + mi * 16 + q * 4 + j;
        const int gn = n0 + wn + ni * 16 + r;
        float v = acc[mi][ni][j];
        const size_t idx = (size_t)gm * N + gn;
        if (EPI == 0) {
          ((__hip_bfloat16*)C)[idx] = f2bf(v);
        } else if (EPI == 1) {
          ((float*)C)[idx] = v + aux[idx];
        } else if (EPI == 2) {
          v = v / (1.0f + expf(-v));
          ((__hip_bfloat16*)C)[idx] = f2bf(v);
        } else {
          ((float*)C)[idx] = v + aux[idx];
        }
      }
}

// ---------------- Flash attention, barrier-free ----------------
// grid: 1024 blocks (heavy-first); 4 independent waves/block; wave owns 16 q-rows.
// 128-key tiles; K from qkv (B-layout native); V from pre-transposed vt (B-layout
// native); P round-trips wave-private LDS (C->A layout); rowsum via ones-MFMA.
__global__ __launch_bounds__(256, 4) void attn_kernel(const __hip_bfloat16* __restrict__ qkv,
                                                      const __hip_bfloat16* __restrict__ vt,
                                                      const float* __restrict__ ts,
                                                      const float* __restrict__ mask,
                                                      const float* __restrict__ decay_rate,
                                                      __hip_bfloat16* __restrict__ out) {
  const int blk = blockIdx.x;
  const int qi = 63 - (blk >> 4);  // heavy diagonals first
  const int bh = blk & 15;
  const int b = bh >> 3, h = bh & 7;
  const int l0 = qi * 64;
  const int tid = threadIdx.x, lane = tid & 63, w = tid >> 6;
  const int lw0 = l0 + w * 16;
  const int r = lane & 15, q = lane >> 4;

  __shared__ __align__(16) __hip_bfloat16 Pl[4][16 * 136];  // wave-private, stride-136 pad
  __hip_bfloat16* Pw = Pl[w];

  const float LOG2E = 1.4426950408889634f;
  const float decay = log1pf(expf(decay_rate[h]));
  const float dfac = decay * (1.0f / 24.0f) * LOG2E;
  const float scale2 = 0.125f * LOG2E;

  bf16x8 qf0, qf1;
  {
    const __hip_bfloat16* qrow = qkv + (size_t)(b * L_SEQ + lw0 + r) * QKV_LD + h * 64 + q * 8;
    qf0 = *(const bf16x8*)qrow;
    qf1 = *(const bf16x8*)(qrow + 32);
  }
  float bq[4];
  for (int j = 0; j < 4; j++) bq[j] = dfac * ts[b * L_SEQ + lw0 + q * 4 + j];

  const __hip_bfloat16* Kbase = qkv + (size_t)b * L_SEQ * QKV_LD + 512 + h * 64;
  const __hip_bfloat16* Vbase = vt + (size_t)bh * 64 * L_SEQ;
  const float* tsb = ts + b * L_SEQ;
  const float* mkb = mask + b * L_SEQ;

  const f32x4 zz = {0.f, 0.f, 0.f, 0.f};
  f32x4 o[4];
  for (int c = 0; c < 4; c++) o[c] = zz;
  f32x4 ls = zz;
  float m_r[4];
  for (int j = 0; j < 4; j++) m_r[j] = -INFINITY;

  bf16x8 onesf;
  for (int i = 0; i < 8; i++) ((short*)&onesf)[i] = (short)0x3F80;  // bf16 1.0

  const int ntiles = (l0 >> 7) + 1;
  for (int kt = 0; kt < ntiles; kt++) {
    const int key0 = kt << 7;
    const int rem = l0 + 64 - key0;             // 64 or >=128
    const int hcend = (rem >= 128) ? 8 : 4;

    // S = Q K^T over up to 128 keys
    f32x4 s[8];
    for (int hc = 0; hc < hcend; hc++) {
      const __hip_bfloat16* kr = Kbase + (size_t)(key0 + hc * 16 + r) * QKV_LD + q * 8;
      bf16x8 k0 = *(const bf16x8*)kr;
      bf16x8 k1 = *(const bf16x8*)(kr + 32);
      f32x4 a = zz;
      a = __builtin_amdgcn_mfma_f32_16x16x32_bf16(qf0, k0, a, 0, 0, 0);
      a = __builtin_amdgcn_mfma_f32_16x16x32_bf16(qf1, k1, a, 0, 0, 0);
      s[hc] = a;
    }

    float bk[8], mk[8];
    for (int hc = 0; hc < hcend; hc++) {
      const int col = key0 + hc * 16 + r;
      bk[hc] = dfac * tsb[col];
      mk[hc] = mkb[col];
    }

    for (int j = 0; j < 4; j++) {
      const int rowg = lw0 + q * 4 + j;
      float lg[8];
      float best = -INFINITY;
      for (int hc = 0; hc < hcend; hc++) {
        const int col = key0 + hc * 16 + r;
        float v = fmaf(s[hc][j], scale2, bk[hc] - bq[j]);  // log2-domain score
        const bool valid = (col <= rowg) && (mk[hc] != 0.f);
        v = valid ? v : -INFINITY;
        lg[hc] = v;
        best = fmaxf(best, v);
      }
      best = fmaxf(best, __shfl_xor(best, 1));
      best = fmaxf(best, __shfl_xor(best, 2));
      best = fmaxf(best, __shfl_xor(best, 4));
      best = fmaxf(best, __shfl_xor(best, 8));
      float mnew = fmaxf(m_r[j], best);
      if (mnew == -INFINITY) mnew = 0.f;  // fully-masked-so-far guard
      const float alpha = exp2f(m_r[j] - mnew);
      m_r[j] = mnew;
      for (int hc = 0; hc < hcend; hc++)
        Pw[(q * 4 + j) * 136 + hc * 16 + r] = f2bf(exp2f(lg[hc] - mnew));
      ls[j] *= alpha;
      for (int c = 0; c < 4; c++) o[c][j] *= alpha;
    }

    // O += P V ; rowsum via ones fragment (no cross-wave sync: Pw is wave-private)
    const int kcend = hcend >> 1;
    for (int kc = 0; kc < kcend; kc++) {
      bf16x8 pf = *(const bf16x8*)(Pw + r * 136 + kc * 32 + q * 8);
      for (int c = 0; c < 4; c++) {
        const __hip_bfloat16* vr = Vbase + (size_t)(c * 16 + r) * L_SEQ + key0 + kc * 32 + q * 8;
        bf16x8 vf = *(const bf16x8*)vr;
        o[c] = __builtin_amdgcn_mfma_f32_16x16x32_bf16(pf, vf, o[c], 0, 0, 0);
      }
      ls = __builtin_amdgcn_mfma_f32_16x16x32_bf16(pf, onesf, ls, 0, 0, 0);
    }
  }

  float inv[4];
  for (int j = 0; j < 4; j++) inv[j] = 1.0f / ls[j];
  for (int c = 0; c < 4; c++)
    for (int j = 0; j < 4; j++) {
      const int rowg = lw0 + q * 4 + j;
      out[(size_t)(b * L_SEQ + rowg) * D_MODEL + h * 64 + c * 16 + r] = f2bf(o[c][j] * inv[j]);
    }
}

// ---------------- Launch ----------------
extern "C" void kernel_launch(void* const* d_in, const int* in_sizes, int n_in,
                              void* d_out, int out_size, void* d_ws, size_t ws_size,
                              hipStream_t stream) {
  const float* x = (const float*)d_in[0];
  const float* ts = (const float*)d_in[1];
  const float* mask = (const float*)d_in[2];
  const float* ln1_g = (const float*)d_in[3];
  const float* ln1_b = (const float*)d_in[4];
  const float* w_qkv = (const float*)d_in[5];
  const float* w_out = (const float*)d_in[6];
  const float* decay = (const float*)d_in[7];
  const float* ln2_g = (const float*)d_in[8];
  const float* ln2_b = (const float*)d_in[9];
  const float* w_ff1 = (const float*)d_in[10];
  const float* w_ff2 = (const float*)d_in[11];

  char* ws = (char*)d_ws;
  // layout (bytes):
  //   [0, 6M)    weights bf16
  //   [6M, 14M)  xn (dead after gemm0) -> vt overlays; both dead before ff1out
  //   [14M, 38M) qkv (dead after attn)
  //   [38M, 46M) attnout -> h
  //   [46M, 62M) x2 (fp32)
  //   ff1out overlays [6M, 38M)
  __hip_bfloat16* wqkv_b = (__hip_bfloat16*)(ws + 0);
  __hip_bfloat16* wout_b = (__hip_bfloat16*)(ws + 1572864);
  __hip_bfloat16* wff1_b = (__hip_bfloat16*)(ws + 2097152);
  __hip_bfloat16* wff2_b = (__hip_bfloat16*)(ws + 4194304);
  __hip_bfloat16* xn = (__hip_bfloat16*)(ws + 6291456);
  __hip_bfloat16* vt = (__hip_bfloat16*)(ws + 6291456);
  __hip_bfloat16* qkv = (__hip_bfloat16*)(ws + 14680064);
  __hip_bfloat16* attnout = (__hip_bfloat16*)(ws + 39845888);
  __hip_bfloat16* h = attnout;
  __hip_bfloat16* ff1out = (__hip_bfloat16*)(ws + 6291456);
  float* x2 = (float*)(ws + 48234496);
  float* out = (float*)d_out;

  const int M = 2 * L_SEQ;  // 8192

  cvt_kernel<<<dim3(768), dim3(256), 0, stream>>>(w_qkv, wqkv_b, 196608);
  cvt_kernel<<<dim3(256), dim3(256), 0, stream>>>(w_out, wout_b, 65536);
  cvt_kernel<<<dim3(1024), dim3(256), 0, stream>>>(w_ff1, wff1_b, 262144);
  cvt_kernel<<<dim3(1024), dim3(256), 0, stream>>>(w_ff2, wff2_b, 262144);

  ln_kernel<<<dim3(M), dim3(256), 0, stream>>>(x, ln1_g, ln1_b, xn);
  gemm_kernel<0><<<dim3(12, 64), dim3(256), 0, stream>>>(xn, wqkv_b, M, 1536, 512, nullptr, qkv);
  vtrans_kernel<<<dim3(2048), dim3(256), 0, stream>>>(qkv, vt);
  attn_kernel<<<dim3(1024), dim3(256), 0, stream>>>(qkv, vt, ts, mask, decay, attnout);
  gemm_kernel<1><<<dim3(4, 64), dim3(256), 0, stream>>>(attnout, wout_b, M, 512, 512, x, x2);
  ln_kernel<<<dim3(M), dim3(256), 0, stream>>>(x2, ln2_g, ln2_b, h);
  gemm_kernel<2><<<dim3(16, 64), dim3(256), 0, stream>>>(h, wff1_b, M, 2048, 512, nullptr, ff1out);
  gemm_kernel<3><<<dim3(4, 64), dim3(256), 0, stream>>>(ff1out, wff2_b, M, 512, 2048, x2, out);
}

// Round 4
// 519.774 us; speedup vs baseline: 1.5243x; 1.5243x over previous
//
#include <hip/hip_runtime.h>
#include <hip/hip_bf16.h>
#include <cmath>

// SparseAttentionBlock: B=2, L=4096, D=512, H=8, dh=64
// Inputs/outputs fp32; internal GEMM pipeline bf16; residual spine fp32.

#define L_SEQ 4096
#define D_MODEL 512
#define N_HEADS 8
#define D_HEAD 64
#define QKV_LD 1536

typedef __attribute__((ext_vector_type(8))) short bf16x8;
typedef __attribute__((ext_vector_type(4))) float f32x4;

__device__ __forceinline__ __hip_bfloat16 f2bf(float v) { return __float2bfloat16(v); }

__device__ __forceinline__ void gl_lds16(const __hip_bfloat16* g, __hip_bfloat16* l) {
  __builtin_amdgcn_global_load_lds((__attribute__((address_space(1))) void*)g,
                                   (__attribute__((address_space(3))) void*)l, 16, 0, 0);
}

// ---------------- fp32 -> bf16 convert (weights) ----------------
__global__ __launch_bounds__(256) void cvt_kernel(const float* __restrict__ src,
                                                  __hip_bfloat16* __restrict__ dst, int n4) {
  const int i = blockIdx.x * 256 + threadIdx.x;
  if (i < n4) {
    const float4 v = ((const float4*)src)[i];
    dst[4 * i + 0] = f2bf(v.x);
    dst[4 * i + 1] = f2bf(v.y);
    dst[4 * i + 2] = f2bf(v.z);
    dst[4 * i + 3] = f2bf(v.w);
  }
}

// ---------------- LayerNorm: fp32 in -> bf16 out ----------------
__global__ __launch_bounds__(256) void ln_kernel(const float* __restrict__ x,
                                                 const float* __restrict__ g,
                                                 const float* __restrict__ b,
                                                 __hip_bfloat16* __restrict__ out) {
  const int row = blockIdx.x;
  const int t = threadIdx.x;
  const float* xr = x + (size_t)row * D_MODEL;
  float v0 = xr[t];
  float v1 = xr[t + 256];
  float s = v0 + v1;
  float qq = v0 * v0 + v1 * v1;
  for (int off = 32; off > 0; off >>= 1) {
    s += __shfl_xor(s, off);
    qq += __shfl_xor(qq, off);
  }
  __shared__ float red[8];
  const int wid = t >> 6;
  if ((t & 63) == 0) { red[wid] = s; red[4 + wid] = qq; }
  __syncthreads();
  s = red[0] + red[1] + red[2] + red[3];
  qq = red[4] + red[5] + red[6] + red[7];
  const float mu = s * (1.0f / 512.0f);
  const float var = fmaxf(qq * (1.0f / 512.0f) - mu * mu, 0.0f);
  const float rstd = rsqrtf(var + 1e-5f);
  __hip_bfloat16* orow = out + (size_t)row * D_MODEL;
  orow[t] = f2bf((v0 - mu) * rstd * g[t] + b[t]);
  orow[t + 256] = f2bf((v1 - mu) * rstd * g[t + 256] + b[t + 256]);
}

// ---------------- V transpose: qkv V-region -> vt[b,h,dh,L] ----------------
__global__ __launch_bounds__(256) void vtrans_kernel(const __hip_bfloat16* __restrict__ qkv,
                                                     __hip_bfloat16* __restrict__ vt) {
  const int gid = blockIdx.x * 256 + threadIdx.x;  // 2*64*4096 threads exactly
  const int l = gid & 4095;
  const int bg = gid >> 12;
  const int b = bg >> 6, g = bg & 63;
  const int h = g >> 3, dg = (g & 7) * 8;
  const __hip_bfloat16* src = qkv + (size_t)(b * L_SEQ + l) * QKV_LD + 1024 + h * 64 + dg;
  bf16x8 v = *(const bf16x8*)src;
  const size_t dbase = (size_t)((b * 8 + h) * 64 + dg) * L_SEQ + l;
  for (int j = 0; j < 8; j++)
    vt[dbase + (size_t)j * L_SEQ] = ((const __hip_bfloat16*)&v)[j];  // coalesced over l
}

// ---------------- GEMM: C[M,N] = A[M,K] @ B[N,K]^T, bf16 in, fp32 accum ----------------
// EPI 0: store bf16   1: += aux(fp32), store fp32   2: silu, store bf16   3: += aux(fp32), store fp32
template <int EPI>
__global__ __launch_bounds__(256) void gemm_kernel(const __hip_bfloat16* __restrict__ A,
                                                   const __hip_bfloat16* __restrict__ B,
                                                   int M, int N, int K,
                                                   const float* __restrict__ aux,
                                                   void* __restrict__ C) {
  __shared__ __align__(16) __hip_bfloat16 As[128 * 32];
  __shared__ __align__(16) __hip_bfloat16 Bs[128 * 32];
  const int tid = threadIdx.x;
  const int lane = tid & 63, w = tid >> 6;
  const int m0 = blockIdx.y * 128, n0 = blockIdx.x * 128;
  const int wm = (w >> 1) * 64, wn = (w & 1) * 64;
  const int r = lane & 15, q = lane >> 4;

  f32x4 acc[4][4];
  const f32x4 zz = {0.f, 0.f, 0.f, 0.f};
  for (int i = 0; i < 4; i++)
    for (int j = 0; j < 4; j++) acc[i][j] = zz;

  for (int k0 = 0; k0 < K; k0 += 32) {
    for (int i = 0; i < 2; i++) {
      const int c = i * 256 + tid;
      const int row = c >> 2, kb = (c & 3) * 8;
      gl_lds16(A + (size_t)(m0 + row) * K + (k0 + kb), As + c * 8);
      gl_lds16(B + (size_t)(n0 + row) * K + (k0 + kb), Bs + c * 8);
    }
    __syncthreads();
    bf16x8 af[4], bfr[4];
    for (int mi = 0; mi < 4; mi++)
      af[mi] = *(const bf16x8*)(As + (wm + mi * 16 + r) * 32 + q * 8);
    for (int ni = 0; ni < 4; ni++)
      bfr[ni] = *(const bf16x8*)(Bs + (wn + ni * 16 + r) * 32 + q * 8);
    for (int mi = 0; mi < 4; mi++)
      for (int ni = 0; ni < 4; ni++)
        acc[mi][ni] = __builtin_amdgcn_mfma_f32_16x16x32_bf16(af[mi], bfr[ni], acc[mi][ni], 0, 0, 0);
    __syncthreads();
  }

  for (int mi = 0; mi < 4; mi++)
    for (int ni = 0; ni < 4; ni++)
      for (int j = 0; j < 4; j++) {
        const int gm = m0 + wm + mi * 16 + q * 4 + j;
        const int gn = n0 + wn + ni * 16 + r;
        float v = acc[mi][ni][j];
        const size_t idx = (size_t)gm * N + gn;
        if (EPI == 0) {
          ((__hip_bfloat16*)C)[idx] = f2bf(v);
        } else if (EPI == 1) {
          ((float*)C)[idx] = v + aux[idx];
        } else if (EPI == 2) {
          v = v / (1.0f + expf(-v));
          ((__hip_bfloat16*)C)[idx] = f2bf(v);
        } else {
          ((float*)C)[idx] = v + aux[idx];
        }
      }
}

// ---------------- Flash attention tile body (compile-time HC => all-register) ----------------
template <int HC>
__device__ __forceinline__ void attn_tile(int key0, int lw0, int r, int q,
                                          const __hip_bfloat16* Kbase,
                                          const __hip_bfloat16* Vbase,
                                          const float* tsb, const float* mkb,
                                          float dfac, float scale2, const float* bq,
                                          const bf16x8& qf0, const bf16x8& qf1,
                                          const bf16x8& onesf,
                                          __hip_bfloat16* Pw,
                                          f32x4* o, f32x4& ls, float* m_r) {
  const f32x4 zz = {0.f, 0.f, 0.f, 0.f};
  f32x4 s[HC];
#pragma unroll
  for (int hc = 0; hc < HC; hc++) {
    const __hip_bfloat16* kr = Kbase + (size_t)(key0 + hc * 16 + r) * QKV_LD + q * 8;
    bf16x8 k0 = *(const bf16x8*)kr;
    bf16x8 k1 = *(const bf16x8*)(kr + 32);
    f32x4 a = zz;
    a = __builtin_amdgcn_mfma_f32_16x16x32_bf16(qf0, k0, a, 0, 0, 0);
    a = __builtin_amdgcn_mfma_f32_16x16x32_bf16(qf1, k1, a, 0, 0, 0);
    s[hc] = a;
  }
  float bk[HC], mk[HC];
#pragma unroll
  for (int hc = 0; hc < HC; hc++) {
    const int col = key0 + hc * 16 + r;
    bk[hc] = dfac * tsb[col];
    mk[hc] = mkb[col];
  }
#pragma unroll
  for (int j = 0; j < 4; j++) {
    const int rowg = lw0 + q * 4 + j;
    float lg[HC];
    float best = -INFINITY;
#pragma unroll
    for (int hc = 0; hc < HC; hc++) {
      const int col = key0 + hc * 16 + r;
      float v = fmaf(s[hc][j], scale2, bk[hc] - bq[j]);  // log2-domain score
      const bool valid = (col <= rowg) && (mk[hc] != 0.f);
      v = valid ? v : -INFINITY;
      lg[hc] = v;
      best = fmaxf(best, v);
    }
    best = fmaxf(best, __shfl_xor(best, 1));
    best = fmaxf(best, __shfl_xor(best, 2));
    best = fmaxf(best, __shfl_xor(best, 4));
    best = fmaxf(best, __shfl_xor(best, 8));
    float mnew = fmaxf(m_r[j], best);
    if (mnew == -INFINITY) mnew = 0.f;  // fully-masked guard
    const float alpha = exp2f(m_r[j] - mnew);
    m_r[j] = mnew;
#pragma unroll
    for (int hc = 0; hc < HC; hc++)
      Pw[(q * 4 + j) * 136 + hc * 16 + r] = f2bf(exp2f(lg[hc] - mnew));
    ls[j] *= alpha;
#pragma unroll
    for (int c = 0; c < 4; c++) o[c][j] *= alpha;
  }
  // O += P V ; rowsum via ones fragment (wave-private LDS: no __syncthreads needed)
#pragma unroll
  for (int kc = 0; kc < HC / 2; kc++) {
    bf16x8 pf = *(const bf16x8*)(Pw + r * 136 + kc * 32 + q * 8);
#pragma unroll
    for (int c = 0; c < 4; c++) {
      const __hip_bfloat16* vr = Vbase + (size_t)(c * 16 + r) * L_SEQ + key0 + kc * 32 + q * 8;
      bf16x8 vf = *(const bf16x8*)vr;
      o[c] = __builtin_amdgcn_mfma_f32_16x16x32_bf16(pf, vf, o[c], 0, 0, 0);
    }
    ls = __builtin_amdgcn_mfma_f32_16x16x32_bf16(pf, onesf, ls, 0, 0, 0);
  }
}

// grid: 1024 blocks (heavy-first); 4 independent waves/block; wave owns 16 q-rows.
__global__ __launch_bounds__(256, 3) void attn_kernel(const __hip_bfloat16* __restrict__ qkv,
                                                      const __hip_bfloat16* __restrict__ vt,
                                                      const float* __restrict__ ts,
                                                      const float* __restrict__ mask,
                                                      const float* __restrict__ decay_rate,
                                                      __hip_bfloat16* __restrict__ out) {
  const int blk = blockIdx.x;
  const int qi = 63 - (blk >> 4);  // heavy diagonals first
  const int bh = blk & 15;
  const int b = bh >> 3, h = bh & 7;
  const int l0 = qi * 64;
  const int tid = threadIdx.x, lane = tid & 63, w = tid >> 6;
  const int lw0 = l0 + w * 16;
  const int r = lane & 15, q = lane >> 4;

  __shared__ __align__(16) __hip_bfloat16 Pl[4][16 * 136];  // wave-private, stride-136 pad
  __hip_bfloat16* Pw = Pl[w];

  const float LOG2E = 1.4426950408889634f;
  const float decay = log1pf(expf(decay_rate[h]));
  const float dfac = decay * (1.0f / 24.0f) * LOG2E;
  const float scale2 = 0.125f * LOG2E;

  bf16x8 qf0, qf1;
  {
    const __hip_bfloat16* qrow = qkv + (size_t)(b * L_SEQ + lw0 + r) * QKV_LD + h * 64 + q * 8;
    qf0 = *(const bf16x8*)qrow;
    qf1 = *(const bf16x8*)(qrow + 32);
  }
  float bq[4];
  for (int j = 0; j < 4; j++) bq[j] = dfac * ts[b * L_SEQ + lw0 + q * 4 + j];

  const __hip_bfloat16* Kbase = qkv + (size_t)b * L_SEQ * QKV_LD + 512 + h * 64;
  const __hip_bfloat16* Vbase = vt + (size_t)bh * 64 * L_SEQ;
  const float* tsb = ts + b * L_SEQ;
  const float* mkb = mask + b * L_SEQ;

  const f32x4 zz = {0.f, 0.f, 0.f, 0.f};
  f32x4 o[4];
  for (int c = 0; c < 4; c++) o[c] = zz;
  f32x4 ls = zz;
  float m_r[4];
  for (int j = 0; j < 4; j++) m_r[j] = -INFINITY;

  bf16x8 onesf;
  for (int i = 0; i < 8; i++) ((short*)&onesf)[i] = (short)0x3F80;  // bf16 1.0

  // qi odd: (l0>>7)+1 full 128-key tiles. qi even: (l0>>7) full tiles + one 64-key tail.
  const int nfull = (qi & 1) ? (l0 >> 7) + 1 : (l0 >> 7);
  for (int kt = 0; kt < nfull; kt++)
    attn_tile<8>(kt << 7, lw0, r, q, Kbase, Vbase, tsb, mkb, dfac, scale2, bq,
                 qf0, qf1, onesf, Pw, o, ls, m_r);
  if (!(qi & 1))
    attn_tile<4>(nfull << 7, lw0, r, q, Kbase, Vbase, tsb, mkb, dfac, scale2, bq,
                 qf0, qf1, onesf, Pw, o, ls, m_r);

  float inv[4];
  for (int j = 0; j < 4; j++) inv[j] = 1.0f / ls[j];
  for (int c = 0; c < 4; c++)
    for (int j = 0; j < 4; j++) {
      const int rowg = lw0 + q * 4 + j;
      out[(size_t)(b * L_SEQ + rowg) * D_MODEL + h * 64 + c * 16 + r] = f2bf(o[c][j] * inv[j]);
    }
}

// ---------------- Launch ----------------
extern "C" void kernel_launch(void* const* d_in, const int* in_sizes, int n_in,
                              void* d_out, int out_size, void* d_ws, size_t ws_size,
                              hipStream_t stream) {
  const float* x = (const float*)d_in[0];
  const float* ts = (const float*)d_in[1];
  const float* mask = (const float*)d_in[2];
  const float* ln1_g = (const float*)d_in[3];
  const float* ln1_b = (const float*)d_in[4];
  const float* w_qkv = (const float*)d_in[5];
  const float* w_out = (const float*)d_in[6];
  const float* decay = (const float*)d_in[7];
  const float* ln2_g = (const float*)d_in[8];
  const float* ln2_b = (const float*)d_in[9];
  const float* w_ff1 = (const float*)d_in[10];
  const float* w_ff2 = (const float*)d_in[11];

  char* ws = (char*)d_ws;
  // layout (bytes):
  //   [0, 6M)    weights bf16
  //   [6M, 14M)  xn (dead after gemm0) -> vt overlays
  //   [14M, 38M) qkv (dead after attn)
  //   [38M, 46M) attnout -> h
  //   [46M, 62M) x2 (fp32)
  //   ff1out overlays [6M, 38M)
  __hip_bfloat16* wqkv_b = (__hip_bfloat16*)(ws + 0);
  __hip_bfloat16* wout_b = (__hip_bfloat16*)(ws + 1572864);
  __hip_bfloat16* wff1_b = (__hip_bfloat16*)(ws + 2097152);
  __hip_bfloat16* wff2_b = (__hip_bfloat16*)(ws + 4194304);
  __hip_bfloat16* xn = (__hip_bfloat16*)(ws + 6291456);
  __hip_bfloat16* vt = (__hip_bfloat16*)(ws + 6291456);
  __hip_bfloat16* qkv = (__hip_bfloat16*)(ws + 14680064);
  __hip_bfloat16* attnout = (__hip_bfloat16*)(ws + 39845888);
  __hip_bfloat16* h = attnout;
  __hip_bfloat16* ff1out = (__hip_bfloat16*)(ws + 6291456);
  float* x2 = (float*)(ws + 48234496);
  float* out = (float*)d_out;

  const int M = 2 * L_SEQ;  // 8192

  cvt_kernel<<<dim3(768), dim3(256), 0, stream>>>(w_qkv, wqkv_b, 196608);
  cvt_kernel<<<dim3(256), dim3(256), 0, stream>>>(w_out, wout_b, 65536);
  cvt_kernel<<<dim3(1024), dim3(256), 0, stream>>>(w_ff1, wff1_b, 262144);
  cvt_kernel<<<dim3(1024), dim3(256), 0, stream>>>(w_ff2, wff2_b, 262144);

  ln_kernel<<<dim3(M), dim3(256), 0, stream>>>(x, ln1_g, ln1_b, xn);
  gemm_kernel<0><<<dim3(12, 64), dim3(256), 0, stream>>>(xn, wqkv_b, M, 1536, 512, nullptr, qkv);
  vtrans_kernel<<<dim3(2048), dim3(256), 0, stream>>>(qkv, vt);
  attn_kernel<<<dim3(1024), dim3(256), 0, stream>>>(qkv, vt, ts, mask, decay, attnout);
  gemm_kernel<1><<<dim3(4, 64), dim3(256), 0, stream>>>(attnout, wout_b, M, 512, 512, x, x2);
  ln_kernel<<<dim3(M), dim3(256), 0, stream>>>(x2, ln2_g, ln2_b, h);
  gemm_kernel<2><<<dim3(16, 64), dim3(256), 0, stream>>>(h, wff1_b, M, 2048, 512, nullptr, ff1out);
  gemm_kernel<3><<<dim3(4, 64), dim3(256), 0, stream>>>(ff1out, wff2_b, M, 512, 2048, x2, out);
}